// Round 8
// baseline (36.666 us; speedup 1.0000x reference)
//
#include <hip/hip_runtime.h>
#include <math.h>

#define NROWS 8192
#define NCOLS 4096
#define RPC 32                     // rows per chunk
#define NCHUNK (NROWS / RPC)       // 256
#define TPB 1024                   // 16 waves/block
#define CPT 2                      // cols per thread (float2)
#define CTILE (TPB * CPT)          // 2048 cols per block
#define NTILE (NCOLS / CTILE)      // 2 -> grid 512 blocks = 2/CU = 8 waves/SIMD
#define F2BLK 128                  // stage-2 blocks
#define CPB2 (NCOLS / F2BLK)       // 32 columns per stage-2 block
#define PARTS 8                    // stage-2 threads per column

typedef float f32x2 __attribute__((ext_vector_type(2)));

// Stage 1: grid (NTILE, NCHUNK); block = 1024 threads, 2 cols/thread.
// 2 blocks/CU at <=64 VGPR -> 8 waves/SIMD for latency hiding.
// Branch-free tail: prefetch row offset clamps to last valid row (wave-uniform
// s_min); da_sh[i]=0 past the last diff, and at the clamp cur==nxt, so the
// tail contributes exactly 0 through the same arithmetic path.
__global__ __launch_bounds__(TPB, 8) void tss_partial_kernel(
    const float* __restrict__ x,
    float* __restrict__ ptss,
    float* __restrict__ pcs)
{
    const int tid   = threadIdx.x;
    const int tile  = blockIdx.x;   // 0..NTILE-1
    const int chunk = blockIdx.y;   // 0..NCHUNK-1
    const int col   = tile * CTILE + tid * CPT;
    const int r0    = chunk * RPC;

    __shared__ float x0[RPC + 1];
    __shared__ float da_sh[RPC];

    if (tid <= RPC) {
        int r = min(r0 + tid, NROWS - 1);
        x0[tid] = x[(size_t)r * NCOLS];
    }
    __syncthreads();
    if (tid < RPC) {
        da_sh[tid] = (r0 + tid + 1 < NROWS) ? (x0[tid + 1] - x0[tid]) : 0.0f;
    }
    __syncthreads();

    const f32x2* row = (const f32x2*)(x + (size_t)r0 * NCOLS + col);
    const int rs = NCOLS / 2;             // row stride in f32x2
    const int maxoff = NROWS - 1 - r0;    // wave-uniform clamp (>= 31)

    float tss0 = 0.f, tss1 = 0.f;
    float cs0 = 0.f, cs1 = 0.f;

    f32x2 cur = row[0];                          // row r0
    f32x2 nxt = row[min(1, maxoff) * rs];        // row r0+1

    #pragma unroll 8
    for (int i = 0; i < RPC; ++i) {
        const int offc = (i + 2 <= RPC) ? (i + 2) : RPC;
        const int off  = min(offc, maxoff);
        f32x2 pf = row[off * rs];

        cs0 += cur.x; cs1 += cur.y;

        const float da = da_sh[i];
        float db, df;
        db = nxt.x - cur.x; df = da - db;
        tss0 += (da * db >= 0.f) ? df : fabsf(df);
        db = nxt.y - cur.y; df = da - db;
        tss1 += (da * db >= 0.f) ? df : fabsf(df);

        cur = nxt;
        nxt = pf;
    }

    f32x2* pt = (f32x2*)(ptss + (size_t)chunk * NCOLS + col);
    f32x2* pc = (f32x2*)(pcs  + (size_t)chunk * NCOLS + col);
    f32x2 tv; tv.x = tss0; tv.y = tss1;
    f32x2 cv; cv.x = cs0;  cv.y = cs1;
    *pt = tv;
    *pc = cv;
}

// Stage 2: 128 blocks x 256 threads; PARTS=8 threads per column, each sums 32
// chunks (coalesced within a wave), LDS combine + tree, per-block (t, t*cs).
__global__ __launch_bounds__(256) void tss_finalize_kernel(
    const float* __restrict__ ptss,
    const float* __restrict__ pcs,
    const float* __restrict__ variance,
    double* __restrict__ blk)     // [F2BLK][2]
{
    const int tid  = threadIdx.x;
    const int part = tid >> 5;          // 0..7
    const int cpos = tid & 31;          // 0..31
    const int j    = blockIdx.x * CPB2 + cpos;

    double tss = 0.0, cs = 0.0;
    #pragma unroll 8
    for (int c = part * (NCHUNK / PARTS); c < (part + 1) * (NCHUNK / PARTS); ++c) {
        tss += (double)ptss[(size_t)c * NCOLS + j];
        cs  += (double)pcs[(size_t)c * NCOLS + j];
    }

    __shared__ double stss[PARTS][CPB2];
    __shared__ double scs[PARTS][CPB2];
    stss[part][cpos] = tss;
    scs[part][cpos]  = cs;
    __syncthreads();

    __shared__ double s1[CPB2];
    __shared__ double s2[CPB2];
    if (tid < CPB2) {
        tss = 0.0; cs = 0.0;
        #pragma unroll
        for (int p = 0; p < PARTS; ++p) { tss += stss[p][tid]; cs += scs[p][tid]; }

        double t = 0.0, tc = 0.0;
        const int jj = blockIdx.x * CPB2 + tid;
        if (jj >= 1) {
            const double var = (double)variance[0];
            const double SQRT_2PI = 2.5066282746310005024;
            const double coef = 1.0 / (SQRT_2PI * var);
            const double score = coef * exp(-(tss * tss) / (2.0 * var * var));
            t  = tan(score);
            tc = t * cs;
        }
        s1[tid] = t; s2[tid] = tc;
    }
    __syncthreads();
    for (int s = CPB2 / 2; s > 0; s >>= 1) {
        if (tid < s) { s1[tid] += s1[tid + s]; s2[tid] += s2[tid + s]; }
        __syncthreads();
    }
    if (tid == 0) {
        blk[2 * blockIdx.x]     = s1[0];
        blk[2 * blockIdx.x + 1] = s2[0];
    }
}

// Stage 3: reduce F2BLK pairs in one wave (each lane takes 2 pairs).
__global__ __launch_bounds__(64) void tss_reduce_kernel(
    const double* __restrict__ blk,
    float* __restrict__ out)
{
    const int tid = threadIdx.x;
    double st  = blk[2 * tid]     + blk[2 * (tid + 64)];
    double stc = blk[2 * tid + 1] + blk[2 * (tid + 64) + 1];
    for (int o = 32; o > 0; o >>= 1) {
        st  += __shfl_down(st, o);
        stc += __shfl_down(stc, o);
    }
    if (tid == 0) out[0] = (float)(stc / st);
}

extern "C" void kernel_launch(void* const* d_in, const int* in_sizes, int n_in,
                              void* d_out, int out_size, void* d_ws, size_t ws_size,
                              hipStream_t stream) {
    const float* x   = (const float*)d_in[0];
    const float* var = (const float*)d_in[1];
    float* out = (float*)d_out;

    float* ptss = (float*)d_ws;                            // NCHUNK*NCOLS f32 (4 MiB)
    float* pcs  = ptss + (size_t)NCHUNK * NCOLS;           // NCHUNK*NCOLS f32 (4 MiB)
    double* blk = (double*)(pcs + (size_t)NCHUNK * NCOLS); // F2BLK*2 doubles

    dim3 g1(NTILE, NCHUNK);
    tss_partial_kernel<<<g1, TPB, 0, stream>>>(x, ptss, pcs);
    tss_finalize_kernel<<<F2BLK, 256, 0, stream>>>(ptss, pcs, var, blk);
    tss_reduce_kernel<<<1, 64, 0, stream>>>(blk, out);
}